// Round 23
// baseline (185.972 us; speedup 1.0000x reference)
//
#include <hip/hip_runtime.h>
#include <hip/hip_bf16.h>

// Problem constants
#define C_DIM  1024
#define NHEAD  16
#define DHEAD  64
#define T_LEN  2048
#define B_SZ   4
#define M_ROWS (B_SZ * T_LEN)   // 8192
#define QKV_N  (3 * C_DIM)      // 3072

typedef __bf16 bf16x8 __attribute__((ext_vector_type(8)));
typedef float  f32x4  __attribute__((ext_vector_type(4)));
typedef unsigned short ushort8_t __attribute__((ext_vector_type(8)));
typedef unsigned int   uint4_t   __attribute__((ext_vector_type(4)));
typedef short          short4_t  __attribute__((ext_vector_type(4)));

#if __has_builtin(__builtin_amdgcn_mfma_f32_16x16x16bf16_1k)
#define HAVE_MFMA_X16 1
#else
#define HAVE_MFMA_X16 0
#endif

__device__ __forceinline__ unsigned short f2bf(float f) {
    union { float f; unsigned int u; } v; v.f = f;
    unsigned int r = v.u + 0x7FFFu + ((v.u >> 16) & 1u);
    return (unsigned short)(r >> 16);
}

__device__ __forceinline__ bf16x8 as_bf16x8(ushort8_t u) {
    return __builtin_bit_cast(bf16x8, u);
}

__device__ __forceinline__ f32x4 mfma16(bf16x8 a, bf16x8 b, f32x4 c) {
    return __builtin_amdgcn_mfma_f32_16x16x32_bf16(a, b, c, 0, 0, 0);
}

// async global->LDS, 16B per lane, dest = wave-uniform base + lane*16
#define GLL16(gsrc, ldst) __builtin_amdgcn_global_load_lds( \
    (const __attribute__((address_space(1))) void*)(gsrc),  \
    (__attribute__((address_space(3))) void*)(ldst), 16, 0, 0)

// bijective XCD-chunked remap (m204)
__device__ __forceinline__ int xcd_remap(int id, int nwg) {
    const int q = nwg >> 3, r = nwg & 7;
    const int xcd = id & 7, off = id >> 3;
    return (xcd < r) ? (xcd * (q + 1) + off) : (r * (q + 1) + (xcd - r) * q + off);
}

// ---------------- fused prep: x fp32->bf16 convert + both weight transposes ----------------
__global__ void k_prep(const float* __restrict__ x,
                       const float* __restrict__ wqkv, const float* __restrict__ wout,
                       unsigned short* __restrict__ xb,
                       unsigned short* __restrict__ wqkvT, unsigned short* __restrict__ woutT) {
    __shared__ float tile[32][33];
    const int bid = blockIdx.x;
    const int tid = threadIdx.x;

    if (bid < 8192) {
        const int i = bid * 256 + tid;
        const float4 v = ((const float4*)x)[i];
        unsigned int lo = (unsigned int)f2bf(v.x) | ((unsigned int)f2bf(v.y) << 16);
        unsigned int hi = (unsigned int)f2bf(v.z) | ((unsigned int)f2bf(v.w) << 16);
        ((uint2*)xb)[i] = make_uint2(lo, hi);
        return;
    }

    const int tb  = bid - 8192;
    const int bxr = tb & 127;
    const int ky  = tb >> 7;
    const bool isQ = (bxr < QKV_N / 32);
    const int bx = isQ ? bxr : bxr - QKV_N / 32;
    const float* w = isQ ? wqkv : wout;
    unsigned short* wT = isQ ? wqkvT : woutT;
    const int N = isQ ? QKV_N : C_DIM;
    const int K = C_DIM;

    const int n0 = bx * 32, k0 = ky * 32;
    const int tx = tid & 31, ty = tid >> 5;
    for (int i = 0; i < 32; i += 8)
        tile[ty + i][tx] = w[(size_t)(k0 + ty + i) * N + (n0 + tx)];
    __syncthreads();
    for (int i = 0; i < 32; i += 8)
        wT[(size_t)(n0 + ty + i) * K + (k0 + tx)] = f2bf(tile[tx][ty + i]);
}

// ---------------- V -> V^T global pre-transpose (fallback if ws too small) ----------------
__global__ void k_transpose_v(const unsigned short* __restrict__ qkv,
                              unsigned short* __restrict__ vtg) {
    __shared__ unsigned short tile[32][33];
    const int tt = blockIdx.x;
    const int dy = blockIdx.y;
    const int bh = dy >> 1, dtile = dy & 1;
    const int b = bh >> 4, h = bh & 15;
    const int t0 = tt * 32, d0 = dtile * 32;
    const int tx = threadIdx.x, ty = threadIdx.y;  // 32 x 8
    const unsigned short* src = qkv + (size_t)b * T_LEN * QKV_N + 2 * C_DIM + h * DHEAD + d0;
    for (int i = 0; i < 32; i += 8)
        tile[ty + i][tx] = src[(size_t)(t0 + ty + i) * QKV_N + tx];
    __syncthreads();
    unsigned short* dst = vtg + ((size_t)bh * DHEAD + d0) * T_LEN + t0;
    for (int i = 0; i < 32; i += 8)
        dst[(size_t)(ty + i) * T_LEN + tx] = tile[tx][ty + i];
}

// ---------------- bf16 GEMM: A[M][K] x Bt[N][K] -> C[M][N] (+bias) ----------------
// R18's proven best: 128x128 tile, BK=64, global_load_lds width-16 staging,
// XOR-swizzled LDS. If vtg != nullptr: V-column blocks write transposed to vtg.
template<int BF16_OUT>
__global__ __launch_bounds__(256) void k_gemm(const unsigned short* __restrict__ A,
                       const unsigned short* __restrict__ Bt,
                       const float* __restrict__ bias,
                       void* __restrict__ C,
                       unsigned short* __restrict__ vtg,
                       int M, int N, int K) {
    __shared__ unsigned short As[128][64];   // linear, 128B rows
    __shared__ unsigned short Bs[128][64];

    const int tid  = threadIdx.x;
    const int lane = tid & 63;
    const int wv   = tid >> 6;
    const int wm = wv >> 1, wn = wv & 1;

    const int nwg = gridDim.x * gridDim.y;
    const int wg  = xcd_remap(blockIdx.y * gridDim.x + blockIdx.x, nwg);
    const int bx = wg % gridDim.x, by = wg / gridDim.x;
    const int m0 = by * 128;
    const int n0 = bx * 128;
    const int lr = lane & 15, lg = lane >> 4;

    f32x4 acc[4][4];
#pragma unroll
    for (int i = 0; i < 4; i++)
#pragma unroll
        for (int j = 0; j < 4; j++) acc[i][j] = (f32x4){0.f, 0.f, 0.f, 0.f};

    const int gr = lane >> 3;
    const int gc = 8 * ((lane & 7) ^ gr);

    for (int kt = 0; kt < K; kt += 64) {
        __syncthreads();
#pragma unroll
        for (int j = 0; j < 4; j++) {
            const int row = 32 * wv + 8 * j;
            GLL16(A  + (size_t)(m0 + row + gr) * K + kt + gc, &As[row][0]);
            GLL16(Bt + (size_t)(n0 + row + gr) * K + kt + gc, &Bs[row][0]);
        }
        __syncthreads();

#pragma unroll
        for (int s = 0; s < 2; s++) {
            const int cb = (s * 64 + lg * 16) ^ ((lr & 7) << 4);
            bf16x8 af[4], bfr[4];
#pragma unroll
            for (int i = 0; i < 4; i++)
                af[i] = as_bf16x8(*(const ushort8_t*)((const char*)&As[wm * 64 + i * 16 + lr][0] + cb));
#pragma unroll
            for (int j = 0; j < 4; j++)
                bfr[j] = as_bf16x8(*(const ushort8_t*)((const char*)&Bs[wn * 64 + j * 16 + lr][0] + cb));
#pragma unroll
            for (int i = 0; i < 4; i++)
#pragma unroll
                for (int j = 0; j < 4; j++)
                    acc[i][j] = mfma16(af[i], bfr[j], acc[i][j]);
        }
    }

    const bool isV = (vtg != nullptr) && (n0 >= 2 * C_DIM);
#pragma unroll
    for (int i = 0; i < 4; i++) {
#pragma unroll
        for (int j = 0; j < 4; j++) {
            const int col = n0 + wn * 64 + j * 16 + lr;
            const float bv = bias ? bias[col] : 0.f;
            if (isV) {
                const int dcol = col - 2 * C_DIM;
                const int hh = dcol >> 6, dd = dcol & 63;
                const int row0 = m0 + wm * 64 + i * 16 + lg * 4;
                const int bb = row0 >> 11, t0 = row0 & (T_LEN - 1);
                const unsigned int p0 = (unsigned int)f2bf(acc[i][j][0] + bv)
                                      | ((unsigned int)f2bf(acc[i][j][1] + bv) << 16);
                const unsigned int p1 = (unsigned int)f2bf(acc[i][j][2] + bv)
                                      | ((unsigned int)f2bf(acc[i][j][3] + bv) << 16);
                *(uint2*)&vtg[(((size_t)(bb * 16 + hh)) * 64 + dd) * T_LEN + t0] = make_uint2(p0, p1);
            } else {
#pragma unroll
                for (int r = 0; r < 4; r++) {
                    const int row = m0 + wm * 64 + i * 16 + lg * 4 + r;
                    const float v = acc[i][j][r] + bv;
                    if (BF16_OUT)
                        ((unsigned short*)C)[(size_t)row * N + col] = f2bf(v);
                    else
                        ((float*)C)[(size_t)row * N + col] = v;
                }
            }
        }
    }
}

// ---------------- flash attention (causal): merged q-tile pair, shared rounds ----------------
// Block handles q-tiles (pr, 31-pr) CONCURRENTLY over r = 0..31-pr: shared rounds
// (r <= pr) serve both tiles with ONE staging + ONE barrier + SHARED K/V ds_reads.
// Rounds per block: 33 -> 17..32 (avg 24.5); compute balanced (33 tile-rounds).
// Register-direct PV (R13); swapped QK^T (q = lane&15 lane-local softmax).
#define KS_OFF(B_, ROW_) (((B_) << 13) + ((ROW_) << 7))
#define VS_OFF(B_, ROW_) (16384 + ((B_) << 13) + ((ROW_) << 7))
#define SCALE2 0.180336880f   // 0.125 * log2(e)
__global__ __launch_bounds__(256, 4) void k_attn(const unsigned short* __restrict__ qkv,
                                                 const unsigned short* __restrict__ vtg,
                                                 unsigned short* __restrict__ out) {
    __shared__ __align__(16) char asmem[32768];

    const int blk = xcd_remap(blockIdx.x, B_SZ * NHEAD * 16);
    const int pr = blk & 15;
    const int h  = (blk >> 4) & 15;
    const int b  = blk >> 8;
    const int bh = b * 16 + h;

    const int tid  = threadIdx.x;
    const int lane = tid & 63;
    const int w    = tid >> 6;
    const int lr = lane & 15, lg = lane >> 4;
    const int gr = lane >> 3;
    const int gc = 8 * ((lane & 7) ^ gr);
    const int ra = w * 16;

    const size_t base = (size_t)b * T_LEN * QKV_N + (size_t)h * DHEAD;
    const unsigned short* Qp = qkv + base;
    const unsigned short* Kp = qkv + base + C_DIM;
    const unsigned short* Vt = vtg + (size_t)bh * DHEAD * T_LEN;

    const int qta = pr, qtb = 31 - pr;
    const int Ra = qta + 1;          // rounds tile a participates
    const int Rm = qtb + 1;          // total rounds (a's prefix is shared)
    const int qwa = qta * 64 + w * 16, qga = qwa + lr;
    const int qwb = qtb * 64 + w * 16, qgb = qwb + lr;

    bf16x8 qfa[2], qfb[2];
#pragma unroll
    for (int s = 0; s < 2; s++) {
        qfa[s] = as_bf16x8(*(const ushort8_t*)&Qp[(size_t)(qwa + lr) * QKV_N + s * 32 + lg * 8]);
        qfb[s] = as_bf16x8(*(const ushort8_t*)&Qp[(size_t)(qwb + lr) * QKV_N + s * 32 + lg * 8]);
    }

    f32x4 oa[4], ob[4];   // O^T[d = fd*16 + lg*4 + rr][q = lr]
#pragma unroll
    for (int f = 0; f < 4; f++) {
        oa[f] = (f32x4){0.f, 0.f, 0.f, 0.f};
        ob[f] = (f32x4){0.f, 0.f, 0.f, 0.f};
    }
    float lpa = 0.f, lpb = 0.f;

    // prologue: stage round 0 into buf 0
    int buf = 0;
    GLL16(Kp + (size_t)(ra + gr) * QKV_N + gc,          asmem + KS_OFF(buf, ra));
    GLL16(Kp + (size_t)(ra + 8 + gr) * QKV_N + gc,      asmem + KS_OFF(buf, ra + 8));
    GLL16(Vt + (size_t)(ra + gr) * T_LEN + gc,          asmem + VS_OFF(buf, ra));
    GLL16(Vt + (size_t)(ra + 8 + gr) * T_LEN + gc,      asmem + VS_OFF(buf, ra + 8));

    for (int r = 0; r < Rm; ++r) {
        const int kb = r * 64;

        asm volatile("s_waitcnt vmcnt(0)" ::: "memory");
        __builtin_amdgcn_s_barrier();
        __builtin_amdgcn_sched_barrier(0);

        if (r + 1 < Rm) {
            const int kn = kb + 64;
            GLL16(Kp + (size_t)(kn + ra + gr) * QKV_N + gc,     asmem + KS_OFF(buf ^ 1, ra));
            GLL16(Kp + (size_t)(kn + ra + 8 + gr) * QKV_N + gc, asmem + KS_OFF(buf ^ 1, ra + 8));
            GLL16(Vt + (size_t)(ra + gr) * T_LEN + kn + gc,     asmem + VS_OFF(buf ^ 1, ra));
            GLL16(Vt + (size_t)(ra + 8 + gr) * T_LEN + kn + gc, asmem + VS_OFF(buf ^ 1, ra + 8));
        }

        const bool aact = (r < Ra);       // wave-uniform

        // ---- swapped QK^T, BOTH tiles, SHARED K-fragment reads ----
        f32x4 s4a[4], s4b[4];
        __builtin_amdgcn_s_setprio(1);
#pragma unroll
        for (int f = 0; f < 4; f++) {
            const int row = f * 16 + lr;
            const bf16x8 kf0 = as_bf16x8(*(const ushort8_t*)
                (asmem + KS_OFF(buf, row) + ((lg * 16) ^ ((lr & 7) << 4))));
            const bf16x8 kf1 = as_bf16x8(*(const ushort8_t*)
                (asmem + KS_OFF(buf, row) + ((64 + lg * 16) ^ ((lr & 7) << 4))));
            f32x4 s = (f32x4){0.f, 0.f, 0.f, 0.f};
            s = mfma16(kf0, qfb[0], s);
            s = mfma16(kf1, qfb[1], s);
            s4b[f] = s;
            if (aact) {
                f32x4 t = (f32x4){0.f, 0.f, 0.f, 0.f};
                t = mfma16(kf0, qfa[0], t);
                t = mfma16(kf1, qfa[1], t);
                s4a[f] = t;
            }
        }
        __builtin_amdgcn_s_setprio(0);

        // ---- shift-free softmax, pack B-frags (exp2 domain) ----
        const bool lastb = (r == Rm - 1);
        const bool lasta = (r == Ra - 1);
        unsigned int pbb[4][2], pba[4][2];
#pragma unroll
        for (int f = 0; f < 4; f++) {
            unsigned short hh[4];
#pragma unroll
            for (int rr = 0; rr < 4; rr++) {
                float sv = fminf(s4b[f][rr] * SCALE2, 72.f);
                if (lastb) {
                    const int kg = kb + f * 16 + lg * 4 + rr;
                    if (kg > qgb) sv = -1e30f;
                }
                const float e = __builtin_amdgcn_exp2f(sv);
                lpb += e;
                hh[rr] = __builtin_bit_cast(unsigned short, (__bf16)e);
            }
            pbb[f][0] = (unsigned int)hh[0] | ((unsigned int)hh[1] << 16);
            pbb[f][1] = (unsigned int)hh[2] | ((unsigned int)hh[3] << 16);
        }
        if (aact) {
#pragma unroll
            for (int f = 0; f < 4; f++) {
                unsigned short hh[4];
#pragma unroll
                for (int rr = 0; rr < 4; rr++) {
                    float sv = fminf(s4a[f][rr] * SCALE2, 72.f);
                    if (lasta) {
                        const int kg = kb + f * 16 + lg * 4 + rr;
                        if (kg > qga) sv = -1e30f;
                    }
                    const float e = __builtin_amdgcn_exp2f(sv);
                    lpa += e;
                    hh[rr] = __builtin_bit_cast(unsigned short, (__bf16)e);
                }
                pba[f][0] = (unsigned int)hh[0] | ((unsigned int)hh[1] << 16);
                pba[f][1] = (unsigned int)hh[2] | ((unsigned int)hh[3] << 16);
            }
        }

        // ---- PV register-direct, BOTH tiles, SHARED V-fragment reads ----
        __builtin_amdgcn_s_setprio(1);
#pragma unroll
        for (int kg = 0; kg < 4; kg++) {
#if HAVE_MFMA_X16
            const short4_t pvb = __builtin_bit_cast(short4_t, make_uint2(pbb[kg][0], pbb[kg][1]));
            const short4_t pva = __builtin_bit_cast(short4_t, make_uint2(pba[kg][0], pba[kg][1]));
#else
            uint4_t pwb; pwb.x = pbb[kg][0]; pwb.y = pbb[kg][1]; pwb.z = 0u; pwb.w = 0u;
            const bf16x8 pvb8 = __builtin_bit_cast(bf16x8, pwb);
            uint4_t pwa; pwa.x = pba[kg][0]; pwa.y = pba[kg][1]; pwa.z = 0u; pwa.w = 0u;
            const bf16x8 pva8 = __builtin_bit_cast(bf16x8, pwa);
#endif
#pragma unroll
            for (int fd = 0; fd < 4; fd++) {
                const int drow = fd * 16 + lr;
                const uint2 va = *(const uint2*)(asmem + VS_OFF(buf, drow) +
                                 ((kg * 32 + lg * 8) ^ ((lr & 7) << 4)));
#if HAVE_MFMA_X16
                const short4_t vas = __builtin_bit_cast(short4_t, va);
                ob[fd] = __builtin_amdgcn_mfma_f32_16x16x16bf16_1k(vas, pvb, ob[fd], 0, 0, 0);
                if (aact)
                    oa[fd] = __builtin_amdgcn_mfma_f32_16x16x16bf16_1k(vas, pva, oa[fd], 0, 0, 0);
#else
                uint4_t vw; vw.x = va.x; vw.y = va.y; vw.z = va.x; vw.w = va.y;
                const bf16x8 vd = __builtin_bit_cast(bf16x8, vw);
                ob[fd] = mfma16(vd, pvb8, ob[fd]);
                if (aact) oa[fd] = mfma16(vd, pva8, oa[fd]);
#endif
            }
        }
        __builtin_amdgcn_s_setprio(0);

        buf ^= 1;
    }

    // ---- l reductions + packed stores, both tiles ----
    lpa += __shfl_xor(lpa, 16, 64);
    lpa += __shfl_xor(lpa, 32, 64);
    lpb += __shfl_xor(lpb, 16, 64);
    lpb += __shfl_xor(lpb, 32, 64);
    const float inva = 1.f / lpa;
    const float invb = 1.f / lpb;

    unsigned short* orowa = out + ((size_t)b * T_LEN + qwa + lr) * C_DIM + h * DHEAD;
    unsigned short* orowb = out + ((size_t)b * T_LEN + qwb + lr) * C_DIM + h * DHEAD;
#pragma unroll
    for (int fd = 0; fd < 4; fd++) {
        unsigned int p0 = (unsigned int)f2bf(oa[fd][0] * inva)
                        | ((unsigned int)f2bf(oa[fd][1] * inva) << 16);
        unsigned int p1 = (unsigned int)f2bf(oa[fd][2] * inva)
                        | ((unsigned int)f2bf(oa[fd][3] * inva) << 16);
        *(uint2*)&orowa[fd * 16 + lg * 4] = make_uint2(p0, p1);
        p0 = (unsigned int)f2bf(ob[fd][0] * invb)
           | ((unsigned int)f2bf(ob[fd][1] * invb) << 16);
        p1 = (unsigned int)f2bf(ob[fd][2] * invb)
           | ((unsigned int)f2bf(ob[fd][3] * invb) << 16);
        *(uint2*)&orowb[fd * 16 + lg * 4] = make_uint2(p0, p1);
    }
}

// ---------------- launcher ----------------
extern "C" void kernel_launch(void* const* d_in, const int* in_sizes, int n_in,
                              void* d_out, int out_size, void* d_ws, size_t ws_size,
                              hipStream_t stream) {
    const float* x      = (const float*)d_in[0];
    const float* w_qkv  = (const float*)d_in[1];
    const float* b_qkv  = (const float*)d_in[2];
    const float* w_out  = (const float*)d_in[3];
    const float* b_out  = (const float*)d_in[4];
    float* out = (float*)d_out;

    char* ws = (char*)d_ws;
    unsigned short* xb    = (unsigned short*)(ws);                      // 16 MB (dead after QKV GEMM)
    unsigned short* wqkvT = (unsigned short*)(ws + 16777216);           //  6 MB
    unsigned short* woutT = (unsigned short*)(ws + 16777216 + 6291456); //  2 MB
    unsigned short* qkv   = (unsigned short*)(ws + 25165824);           // 48 MB
    unsigned short* attn  = (unsigned short*)(ws + 75497472);           // 16 MB

    const size_t VTG_OFF = 92274688ull;
    const bool fused_vt = (ws_size >= VTG_OFF + 16777216ull);
    unsigned short* vtg = fused_vt ? (unsigned short*)(ws + VTG_OFF)
                                   : (unsigned short*)(ws);  // xb region (dead after GEMM)

    // fused prep: x convert + both weight transposes in ONE dispatch
    k_prep<<<8192 + 4096, 256, 0, stream>>>(x, w_qkv, w_out, xb, wqkvT, woutT);
    // QKV GEMM: R18-proven BK=64 kernel (fused V^T epilogue)
    k_gemm<1><<<dim3(QKV_N / 128, M_ROWS / 128), 256, 0, stream>>>(
        xb, wqkvT, b_qkv, qkv, fused_vt ? vtg : nullptr, M_ROWS, QKV_N, C_DIM);
    if (!fused_vt)
        k_transpose_v<<<dim3(T_LEN / 32, 64 * 2), dim3(32, 8), 0, stream>>>(qkv, vtg);
    // causal attention (merged q-tile pairs, register-direct PV)
    k_attn<<<B_SZ * NHEAD * 16, 256, 0, stream>>>(qkv, vtg, attn);
    // output projection
    k_gemm<0><<<dim3(C_DIM / 128, M_ROWS / 128), 256, 0, stream>>>(
        attn, woutT, b_out, out, nullptr, M_ROWS, C_DIM, C_DIM);
}

// Round 24
// 165.809 us; speedup vs baseline: 1.1216x; 1.1216x over previous
//
#include <hip/hip_runtime.h>
#include <hip/hip_bf16.h>

// Problem constants
#define C_DIM  1024
#define NHEAD  16
#define DHEAD  64
#define T_LEN  2048
#define B_SZ   4
#define M_ROWS (B_SZ * T_LEN)   // 8192
#define QKV_N  (3 * C_DIM)      // 3072

typedef __bf16 bf16x8 __attribute__((ext_vector_type(8)));
typedef float  f32x4  __attribute__((ext_vector_type(4)));
typedef unsigned short ushort8_t __attribute__((ext_vector_type(8)));
typedef unsigned int   uint4_t   __attribute__((ext_vector_type(4)));
typedef short          short4_t  __attribute__((ext_vector_type(4)));

#if __has_builtin(__builtin_amdgcn_mfma_f32_16x16x16bf16_1k)
#define HAVE_MFMA_X16 1
#else
#define HAVE_MFMA_X16 0
#endif

__device__ __forceinline__ unsigned short f2bf(float f) {
    union { float f; unsigned int u; } v; v.f = f;
    unsigned int r = v.u + 0x7FFFu + ((v.u >> 16) & 1u);
    return (unsigned short)(r >> 16);
}

__device__ __forceinline__ bf16x8 as_bf16x8(ushort8_t u) {
    return __builtin_bit_cast(bf16x8, u);
}

__device__ __forceinline__ f32x4 mfma16(bf16x8 a, bf16x8 b, f32x4 c) {
    return __builtin_amdgcn_mfma_f32_16x16x32_bf16(a, b, c, 0, 0, 0);
}

// async global->LDS, 16B per lane, dest = wave-uniform base + lane*16
#define GLL16(gsrc, ldst) __builtin_amdgcn_global_load_lds( \
    (const __attribute__((address_space(1))) void*)(gsrc),  \
    (__attribute__((address_space(3))) void*)(ldst), 16, 0, 0)

// bijective XCD-chunked remap (m204)
__device__ __forceinline__ int xcd_remap(int id, int nwg) {
    const int q = nwg >> 3, r = nwg & 7;
    const int xcd = id & 7, off = id >> 3;
    return (xcd < r) ? (xcd * (q + 1) + off) : (r * (q + 1) + (xcd - r) * q + off);
}

// ---------------- fused prep: x fp32->bf16 convert + both weight transposes ----------------
// blocks [0, 8192): convert x (float4 per thread)
// blocks [8192, 12288): 32x32 transpose tiles; first 96 x-tiles per k-row = w_qkv, rest = w_out
__global__ void k_prep(const float* __restrict__ x,
                       const float* __restrict__ wqkv, const float* __restrict__ wout,
                       unsigned short* __restrict__ xb,
                       unsigned short* __restrict__ wqkvT, unsigned short* __restrict__ woutT) {
    __shared__ float tile[32][33];
    const int bid = blockIdx.x;
    const int tid = threadIdx.x;

    if (bid < 8192) {
        const int i = bid * 256 + tid;          // n4 = 8192*1024/4 = 2097152 = 8192*256
        const float4 v = ((const float4*)x)[i];
        unsigned int lo = (unsigned int)f2bf(v.x) | ((unsigned int)f2bf(v.y) << 16);
        unsigned int hi = (unsigned int)f2bf(v.z) | ((unsigned int)f2bf(v.w) << 16);
        ((uint2*)xb)[i] = make_uint2(lo, hi);
        return;
    }

    const int tb  = bid - 8192;                 // 4096 transpose tiles
    const int bxr = tb & 127;                   // x-tile 0..127
    const int ky  = tb >> 7;                    // k-tile 0..31
    const bool isQ = (bxr < QKV_N / 32);
    const int bx = isQ ? bxr : bxr - QKV_N / 32;
    const float* w = isQ ? wqkv : wout;
    unsigned short* wT = isQ ? wqkvT : woutT;
    const int N = isQ ? QKV_N : C_DIM;
    const int K = C_DIM;

    const int n0 = bx * 32, k0 = ky * 32;
    const int tx = tid & 31, ty = tid >> 5;     // 32 x 8
    for (int i = 0; i < 32; i += 8)
        tile[ty + i][tx] = w[(size_t)(k0 + ty + i) * N + (n0 + tx)];
    __syncthreads();
    for (int i = 0; i < 32; i += 8)
        wT[(size_t)(n0 + ty + i) * K + (k0 + tx)] = f2bf(tile[tx][ty + i]);
}

// ---------------- V -> V^T global pre-transpose (fallback if ws too small) ----------------
__global__ void k_transpose_v(const unsigned short* __restrict__ qkv,
                              unsigned short* __restrict__ vtg) {
    __shared__ unsigned short tile[32][33];
    const int tt = blockIdx.x;
    const int dy = blockIdx.y;
    const int bh = dy >> 1, dtile = dy & 1;
    const int b = bh >> 4, h = bh & 15;
    const int t0 = tt * 32, d0 = dtile * 32;
    const int tx = threadIdx.x, ty = threadIdx.y;  // 32 x 8
    const unsigned short* src = qkv + (size_t)b * T_LEN * QKV_N + 2 * C_DIM + h * DHEAD + d0;
    for (int i = 0; i < 32; i += 8)
        tile[ty + i][tx] = src[(size_t)(t0 + ty + i) * QKV_N + tx];
    __syncthreads();
    unsigned short* dst = vtg + ((size_t)bh * DHEAD + d0) * T_LEN + t0;
    for (int i = 0; i < 32; i += 8)
        dst[(size_t)(ty + i) * T_LEN + tx] = tile[tx][ty + i];
}

// ---------------- bf16 GEMM: A[M][K] x Bt[N][K] -> C[M][N] (+bias) ----------------
// R18's proven best: 128x128 tile, BK=64, global_load_lds width-16 staging,
// XOR-swizzled LDS (zero bank conflicts measured). ~74 us / 715 TF on QKV shape.
// If vtg != nullptr (QKV GEMM): V-column blocks (n0 >= 2048) write their tile
// TRANSPOSED to vtg[bh][d][t] instead of qkv.
template<int BF16_OUT>
__global__ __launch_bounds__(256) void k_gemm(const unsigned short* __restrict__ A,
                       const unsigned short* __restrict__ Bt,
                       const float* __restrict__ bias,
                       void* __restrict__ C,
                       unsigned short* __restrict__ vtg,
                       int M, int N, int K) {
    __shared__ unsigned short As[128][64];   // linear, 128B rows
    __shared__ unsigned short Bs[128][64];

    const int tid  = threadIdx.x;
    const int lane = tid & 63;
    const int wv   = tid >> 6;
    const int wm = wv >> 1, wn = wv & 1;

    const int nwg = gridDim.x * gridDim.y;
    const int wg  = xcd_remap(blockIdx.y * gridDim.x + blockIdx.x, nwg);
    const int bx = wg % gridDim.x, by = wg / gridDim.x;
    const int m0 = by * 128;
    const int n0 = bx * 128;
    const int lr = lane & 15, lg = lane >> 4;

    f32x4 acc[4][4];
#pragma unroll
    for (int i = 0; i < 4; i++)
#pragma unroll
        for (int j = 0; j < 4; j++) acc[i][j] = (f32x4){0.f, 0.f, 0.f, 0.f};

    const int gr = lane >> 3;
    const int gc = 8 * ((lane & 7) ^ gr);

    for (int kt = 0; kt < K; kt += 64) {
        __syncthreads();
#pragma unroll
        for (int j = 0; j < 4; j++) {
            const int row = 32 * wv + 8 * j;
            GLL16(A  + (size_t)(m0 + row + gr) * K + kt + gc, &As[row][0]);
            GLL16(Bt + (size_t)(n0 + row + gr) * K + kt + gc, &Bs[row][0]);
        }
        __syncthreads();

#pragma unroll
        for (int s = 0; s < 2; s++) {
            const int cb = (s * 64 + lg * 16) ^ ((lr & 7) << 4);
            bf16x8 af[4], bfr[4];
#pragma unroll
            for (int i = 0; i < 4; i++)
                af[i] = as_bf16x8(*(const ushort8_t*)((const char*)&As[wm * 64 + i * 16 + lr][0] + cb));
#pragma unroll
            for (int j = 0; j < 4; j++)
                bfr[j] = as_bf16x8(*(const ushort8_t*)((const char*)&Bs[wn * 64 + j * 16 + lr][0] + cb));
#pragma unroll
            for (int i = 0; i < 4; i++)
#pragma unroll
                for (int j = 0; j < 4; j++)
                    acc[i][j] = mfma16(af[i], bfr[j], acc[i][j]);
        }
    }

    const bool isV = (vtg != nullptr) && (n0 >= 2 * C_DIM);
#pragma unroll
    for (int i = 0; i < 4; i++) {
#pragma unroll
        for (int j = 0; j < 4; j++) {
            const int col = n0 + wn * 64 + j * 16 + lr;
            const float bv = bias ? bias[col] : 0.f;
            if (isV) {
                // transposed write: vtg[bh][d][t], 4 consecutive t per lane
                const int dcol = col - 2 * C_DIM;          // 0..1023
                const int hh = dcol >> 6, dd = dcol & 63;
                const int row0 = m0 + wm * 64 + i * 16 + lg * 4;
                const int bb = row0 >> 11, t0 = row0 & (T_LEN - 1);
                const unsigned int p0 = (unsigned int)f2bf(acc[i][j][0] + bv)
                                      | ((unsigned int)f2bf(acc[i][j][1] + bv) << 16);
                const unsigned int p1 = (unsigned int)f2bf(acc[i][j][2] + bv)
                                      | ((unsigned int)f2bf(acc[i][j][3] + bv) << 16);
                *(uint2*)&vtg[(((size_t)(bb * 16 + hh)) * 64 + dd) * T_LEN + t0] = make_uint2(p0, p1);
            } else {
#pragma unroll
                for (int r = 0; r < 4; r++) {
                    const int row = m0 + wm * 64 + i * 16 + lg * 4 + r;
                    const float v = acc[i][j][r] + bv;
                    if (BF16_OUT)
                        ((unsigned short*)C)[(size_t)row * N + col] = f2bf(v);
                    else
                        ((float*)C)[(size_t)row * N + col] = v;
                }
            }
        }
    }
}

// ---------------- flash attention (causal): register-direct PV, 4 blocks/CU ----------------
#define KS_OFF(B_, ROW_) (((B_) << 13) + ((ROW_) << 7))
#define VS_OFF(B_, ROW_) (16384 + ((B_) << 13) + ((ROW_) << 7))
#define SCALE2 0.180336880f   // 0.125 * log2(e)
__global__ __launch_bounds__(256, 4) void k_attn(const unsigned short* __restrict__ qkv,
                                                 const unsigned short* __restrict__ vtg,
                                                 unsigned short* __restrict__ out) {
    __shared__ __align__(16) char asmem[32768];

    const int blk = xcd_remap(blockIdx.x, B_SZ * NHEAD * 16);
    const int pr = blk & 15;
    const int h  = (blk >> 4) & 15;
    const int b  = blk >> 8;
    const int bh = b * 16 + h;

    const int tid  = threadIdx.x;
    const int lane = tid & 63;
    const int w    = tid >> 6;
    const int lr = lane & 15, lg = lane >> 4;
    const int gr = lane >> 3;
    const int gc = 8 * ((lane & 7) ^ gr);
    const int ra = w * 16;

    const size_t base = (size_t)b * T_LEN * QKV_N + (size_t)h * DHEAD;
    const unsigned short* Qp = qkv + base;
    const unsigned short* Kp = qkv + base + C_DIM;
    const unsigned short* Vt = vtg + (size_t)bh * DHEAD * T_LEN;

    int buf = 0;
    for (int t = 0; t < 2; t++) {
        const int qt = (t == 0) ? pr : (31 - pr);
        const int qw = qt * 64 + w * 16;
        const int qg = qw + lr;
        const int R  = qt + 1;

        bf16x8 qf[2];
#pragma unroll
        for (int s = 0; s < 2; s++)
            qf[s] = as_bf16x8(*(const ushort8_t*)&Qp[(size_t)(qw + lr) * QKV_N + s * 32 + lg * 8]);

        f32x4 o[4];   // o[fd][rr] = O^T[d = fd*16 + lg*4 + rr][q = lr]
#pragma unroll
        for (int f = 0; f < 4; f++) o[f] = (f32x4){0.f, 0.f, 0.f, 0.f};
        float lp = 0.f;

        GLL16(Kp + (size_t)(ra + gr) * QKV_N + gc,          asmem + KS_OFF(buf, ra));
        GLL16(Kp + (size_t)(ra + 8 + gr) * QKV_N + gc,      asmem + KS_OFF(buf, ra + 8));
        GLL16(Vt + (size_t)(ra + gr) * T_LEN + gc,          asmem + VS_OFF(buf, ra));
        GLL16(Vt + (size_t)(ra + 8 + gr) * T_LEN + gc,      asmem + VS_OFF(buf, ra + 8));

        for (int r = 0; r < R; ++r) {
            const int kb = r * 64;

            asm volatile("s_waitcnt vmcnt(0)" ::: "memory");
            __builtin_amdgcn_s_barrier();
            __builtin_amdgcn_sched_barrier(0);

            if (r + 1 < R) {
                const int kn = kb + 64;
                GLL16(Kp + (size_t)(kn + ra + gr) * QKV_N + gc,     asmem + KS_OFF(buf ^ 1, ra));
                GLL16(Kp + (size_t)(kn + ra + 8 + gr) * QKV_N + gc, asmem + KS_OFF(buf ^ 1, ra + 8));
                GLL16(Vt + (size_t)(ra + gr) * T_LEN + kn + gc,     asmem + VS_OFF(buf ^ 1, ra));
                GLL16(Vt + (size_t)(ra + 8 + gr) * T_LEN + kn + gc, asmem + VS_OFF(buf ^ 1, ra + 8));
            }

            f32x4 s4[4];
            __builtin_amdgcn_s_setprio(1);
#pragma unroll
            for (int f = 0; f < 4; f++) {
                const int row = f * 16 + lr;
                const bf16x8 kf0 = as_bf16x8(*(const ushort8_t*)
                    (asmem + KS_OFF(buf, row) + ((lg * 16) ^ ((lr & 7) << 4))));
                const bf16x8 kf1 = as_bf16x8(*(const ushort8_t*)
                    (asmem + KS_OFF(buf, row) + ((64 + lg * 16) ^ ((lr & 7) << 4))));
                f32x4 s = (f32x4){0.f, 0.f, 0.f, 0.f};
                s = mfma16(kf0, qf[0], s);
                s = mfma16(kf1, qf[1], s);
                s4[f] = s;
            }
            __builtin_amdgcn_s_setprio(0);

            const bool last = (r == R - 1);
            unsigned int pb[4][2];
#pragma unroll
            for (int f = 0; f < 4; f++) {
                unsigned short hh[4];
#pragma unroll
                for (int rr = 0; rr < 4; rr++) {
                    float sv = fminf(s4[f][rr] * SCALE2, 72.f);
                    if (last) {
                        const int kg = kb + f * 16 + lg * 4 + rr;
                        if (kg > qg) sv = -1e30f;
                    }
                    const float e = __builtin_amdgcn_exp2f(sv);
                    lp += e;
                    hh[rr] = __builtin_bit_cast(unsigned short, (__bf16)e);
                }
                pb[f][0] = (unsigned int)hh[0] | ((unsigned int)hh[1] << 16);
                pb[f][1] = (unsigned int)hh[2] | ((unsigned int)hh[3] << 16);
            }

            __builtin_amdgcn_s_setprio(1);
#pragma unroll
            for (int kg = 0; kg < 4; kg++) {
#if HAVE_MFMA_X16
                const short4_t pbv = __builtin_bit_cast(short4_t,
                    make_uint2(pb[kg][0], pb[kg][1]));
#else
                uint4_t pw;
                pw.x = pb[kg][0]; pw.y = pb[kg][1]; pw.z = 0u; pw.w = 0u;
                const bf16x8 pbv8 = __builtin_bit_cast(bf16x8, pw);
#endif
#pragma unroll
                for (int fd = 0; fd < 4; fd++) {
                    const int drow = fd * 16 + lr;
                    const uint2 va = *(const uint2*)(asmem + VS_OFF(buf, drow) +
                                     ((kg * 32 + lg * 8) ^ ((lr & 7) << 4)));
#if HAVE_MFMA_X16
                    o[fd] = __builtin_amdgcn_mfma_f32_16x16x16bf16_1k(
                        __builtin_bit_cast(short4_t, va), pbv, o[fd], 0, 0, 0);
#else
                    uint4_t vw;
                    vw.x = va.x; vw.y = va.y; vw.z = va.x; vw.w = va.y;
                    o[fd] = mfma16(__builtin_bit_cast(bf16x8, vw), pbv8, o[fd]);
#endif
                }
            }
            __builtin_amdgcn_s_setprio(0);

            buf ^= 1;
        }

        lp += __shfl_xor(lp, 16, 64);
        lp += __shfl_xor(lp, 32, 64);
        const float inv = 1.f / lp;

        unsigned short* orow = out + ((size_t)b * T_LEN + qw + lr) * C_DIM + h * DHEAD;
#pragma unroll
        for (int fd = 0; fd < 4; fd++) {
            const unsigned int p0 = (unsigned int)f2bf(o[fd][0] * inv)
                                  | ((unsigned int)f2bf(o[fd][1] * inv) << 16);
            const unsigned int p1 = (unsigned int)f2bf(o[fd][2] * inv)
                                  | ((unsigned int)f2bf(o[fd][3] * inv) << 16);
            *(uint2*)&orow[fd * 16 + lg * 4] = make_uint2(p0, p1);
        }
    }
}

// ---------------- launcher ----------------
extern "C" void kernel_launch(void* const* d_in, const int* in_sizes, int n_in,
                              void* d_out, int out_size, void* d_ws, size_t ws_size,
                              hipStream_t stream) {
    const float* x      = (const float*)d_in[0];
    const float* w_qkv  = (const float*)d_in[1];
    const float* b_qkv  = (const float*)d_in[2];
    const float* w_out  = (const float*)d_in[3];
    const float* b_out  = (const float*)d_in[4];
    float* out = (float*)d_out;

    char* ws = (char*)d_ws;
    unsigned short* xb    = (unsigned short*)(ws);                      // 16 MB (dead after QKV GEMM)
    unsigned short* wqkvT = (unsigned short*)(ws + 16777216);           //  6 MB
    unsigned short* woutT = (unsigned short*)(ws + 16777216 + 6291456); //  2 MB
    unsigned short* qkv   = (unsigned short*)(ws + 25165824);           // 48 MB
    unsigned short* attn  = (unsigned short*)(ws + 75497472);           // 16 MB

    const size_t VTG_OFF = 92274688ull;
    const bool fused_vt = (ws_size >= VTG_OFF + 16777216ull);
    unsigned short* vtg = fused_vt ? (unsigned short*)(ws + VTG_OFF)
                                   : (unsigned short*)(ws);  // xb region (dead after GEMM)

    // fused prep: x convert + both weight transposes in ONE dispatch
    k_prep<<<8192 + 4096, 256, 0, stream>>>(x, w_qkv, w_out, xb, wqkvT, woutT);
    // QKV GEMM: R18-proven BK=64 kernel (fused V^T epilogue)
    k_gemm<1><<<dim3(QKV_N / 128, M_ROWS / 128), 256, 0, stream>>>(
        xb, wqkvT, b_qkv, qkv, fused_vt ? vtg : nullptr, M_ROWS, QKV_N, C_DIM);
    if (!fused_vt)
        k_transpose_v<<<dim3(T_LEN / 32, 64 * 2), dim3(32, 8), 0, stream>>>(qkv, vtg);
    // causal attention (register-direct PV, 4 blocks/CU)
    k_attn<<<B_SZ * NHEAD * 16, 256, 0, stream>>>(qkv, vtg, attn);
    // output projection
    k_gemm<0><<<dim3(C_DIM / 128, M_ROWS / 128), 256, 0, stream>>>(
        attn, woutT, b_out, out, nullptr, M_ROWS, C_DIM, C_DIM);
}